// Round 9
// baseline (727.897 us; speedup 1.0000x reference)
//
#include <hip/hip_runtime.h>

typedef __bf16 bf16_t;
typedef __bf16 bf16x8 __attribute__((ext_vector_type(8)));
typedef __bf16 bf16x4 __attribute__((ext_vector_type(4)));
typedef float  floatx4 __attribute__((ext_vector_type(4)));

#define D_MODEL 1024
#define S_LEN   2048
#define NHEAD   16
#define DK      64
#define BATCH   4
#define MROWS   (BATCH * S_LEN)   // 8192
// 1/sqrt(64) * log2(e): fold into Q so scores arrive in exp2 domain
#define QSCALE  0.18033688011112042f

__device__ __forceinline__ void load_lds16(const void* gsrc, void* ldst) {
  __builtin_amdgcn_global_load_lds(
      (const __attribute__((address_space(1))) void*)gsrc,
      (__attribute__((address_space(3))) void*)ldst, 16, 0, 0);
}

__device__ __forceinline__ unsigned pack_bf16(float a, float b) {
  union { bf16_t h[2]; unsigned u; } t;
  t.h[0] = (bf16_t)a; t.h[1] = (bf16_t)b;
  return t.u;
}

__device__ __forceinline__ float bperm_f(int addr, float v) {
  union { float f; int i; } in, out;
  in.f = v;
  out.i = __builtin_amdgcn_ds_bpermute(addr, in.i);
  return out.f;
}

// ---------------------------------------------------------------------------
// MERGED prep kernel (one launch instead of two):
//   planes y=0..2: fp32->bf16 convert of Q/K/V into abf [3][8192][1024]
//   plane  y=3, x<1024: weight transpose+cvt (body verbatim from the
//   round-0-verified transpose_w_kernel; x encodes (n-blk, k-blk, z)).
// ---------------------------------------------------------------------------
__global__ __launch_bounds__(256)
void prep_kernel(const float* __restrict__ Q, const float* __restrict__ K,
                 const float* __restrict__ V, bf16_t* __restrict__ Abf,
                 const float* __restrict__ W0, const float* __restrict__ W1,
                 const float* __restrict__ W2, const float* __restrict__ W3,
                 bf16_t* __restrict__ T0, bf16_t* __restrict__ T1,
                 bf16_t* __restrict__ T2, bf16_t* __restrict__ T3)
{
  const int plane = blockIdx.y;
  const int tid = threadIdx.x;

  if (plane < 3) {
    const float* src = plane == 0 ? Q : (plane == 1 ? K : V);
    bf16_t* dst = Abf + ((size_t)plane << 23);
    const size_t off = ((size_t)blockIdx.x * 256 + tid) * 8;
    floatx4 a = *(const floatx4*)&src[off];
    floatx4 b = *(const floatx4*)&src[off + 4];
    bf16x8 o;
    o[0] = (bf16_t)a[0]; o[1] = (bf16_t)a[1];
    o[2] = (bf16_t)a[2]; o[3] = (bf16_t)a[3];
    o[4] = (bf16_t)b[0]; o[5] = (bf16_t)b[1];
    o[6] = (bf16_t)b[2]; o[7] = (bf16_t)b[3];
    *(bf16x8*)&dst[off] = o;
    return;
  }

  // plane == 3: weight transpose. 1024 active blocks.
  const int bx = blockIdx.x;
  if (bx >= 1024) return;
  const int z = bx >> 8;
  const float* W = z == 0 ? W0 : (z == 1 ? W1 : (z == 2 ? W2 : W3));
  bf16_t* Wt     = z == 0 ? T0 : (z == 1 ? T1 : (z == 2 ? T2 : T3));

  __shared__ float tile[64][65];
  const int x0 = (bx & 15) * 64;          // n
  const int y0 = ((bx >> 4) & 15) * 64;   // k
  const int r = tid >> 4;
  const int c = (tid & 15) << 2;
#pragma unroll
  for (int p = 0; p < 4; p++) {
    floatx4 v = *(const floatx4*)&W[(size_t)(y0 + p * 16 + r) * D_MODEL + x0 + c];
    tile[p * 16 + r][c + 0] = v[0];
    tile[p * 16 + r][c + 1] = v[1];
    tile[p * 16 + r][c + 2] = v[2];
    tile[p * 16 + r][c + 3] = v[3];
  }
  __syncthreads();
#pragma unroll
  for (int p = 0; p < 4; p++) {
    int row = p * 16 + r;
    bf16x4 o;
    o[0] = (bf16_t)tile[c + 0][row];
    o[1] = (bf16_t)tile[c + 1][row];
    o[2] = (bf16_t)tile[c + 2][row];
    o[3] = (bf16_t)tile[c + 3][row];
    *(bf16x4*)&Wt[(size_t)(x0 + row) * D_MODEL + y0 + c] = o;
  }
}

// ---------------------------------------------------------------------------
// Standalone weight transpose (fallback path only).
// ---------------------------------------------------------------------------
__global__ __launch_bounds__(256)
void transpose_w_kernel(const float* __restrict__ W0, const float* __restrict__ W1,
                        const float* __restrict__ W2, const float* __restrict__ W3,
                        bf16_t* __restrict__ T0, bf16_t* __restrict__ T1,
                        bf16_t* __restrict__ T2, bf16_t* __restrict__ T3)
{
  const int z = blockIdx.z;
  const float* W = z == 0 ? W0 : (z == 1 ? W1 : (z == 2 ? W2 : W3));
  bf16_t* Wt     = z == 0 ? T0 : (z == 1 ? T1 : (z == 2 ? T2 : T3));

  __shared__ float tile[64][65];
  const int x0 = blockIdx.x * 64;         // n
  const int y0 = blockIdx.y * 64;         // k
  const int tid = threadIdx.x;
  const int r = tid >> 4;
  const int c = (tid & 15) << 2;
#pragma unroll
  for (int p = 0; p < 4; p++) {
    floatx4 v = *(const floatx4*)&W[(size_t)(y0 + p * 16 + r) * D_MODEL + x0 + c];
    tile[p * 16 + r][c + 0] = v[0];
    tile[p * 16 + r][c + 1] = v[1];
    tile[p * 16 + r][c + 2] = v[2];
    tile[p * 16 + r][c + 3] = v[3];
  }
  __syncthreads();
#pragma unroll
  for (int p = 0; p < 4; p++) {
    int row = p * 16 + r;
    bf16x4 o;
    o[0] = (bf16_t)tile[c + 0][row];
    o[1] = (bf16_t)tile[c + 1][row];
    o[2] = (bf16_t)tile[c + 2][row];
    o[3] = (bf16_t)tile[c + 3][row];
    *(bf16x4*)&Wt[(size_t)(x0 + row) * D_MODEL + y0 + c] = o;
  }
}

// ---------------------------------------------------------------------------
// QKV projection, m97-structure, ALL-bf16 (round-8 verified @91us).
// Round-9: __launch_bounds__(256, 6) — request 6 blocks/CU (VGPR was 84,
// budget at 6 waves/EU is 85, so the request is free). grid 1536 = 6x256
// exactly one balanced round; the implicit 6-deep wave overlap (m114) is
// what hides the serial-loop staging latency.
// ---------------------------------------------------------------------------
__global__ __launch_bounds__(256, 6)
void qkv_bf16_kernel(const bf16_t* __restrict__ Abf, const bf16_t* __restrict__ Wcat,
                     const float* __restrict__ bq, const float* __restrict__ bk,
                     const float* __restrict__ bv,
                     bf16_t* __restrict__ qo, bf16_t* __restrict__ ko,
                     bf16_t* __restrict__ vo)
{
  __shared__ bf16_t As[128 * 32];
  __shared__ bf16_t Bs[128 * 32];

  // XCD-locality decode (legacy-verified): the 8 blocks sharing one (z,y)
  // A-stripe land on one XCD (L % 8 == s % 8).
  const int L = blockIdx.x + 24 * blockIdx.y;     // 0..1535
  const int j = (L >> 3) & 7;
  const int s = ((L >> 6) << 3) | (L & 7);        // stripe 0..191
  const int z = s >> 6;                           // projection
  const int n0g = (((z << 3) | j)) << 7;          // global n over 3072
  const int m0 = (s & 63) << 7;

  const bf16_t* A = Abf + ((size_t)z << 23);

  const int tid = threadIdx.x;
  const int lane = tid & 63;
  const int w = tid >> 6;
  const int l15 = lane & 15;
  const int quad = lane >> 4;
  const int wy = (w >> 1) << 6;
  const int wx = (w & 1) << 6;
  const int w64 = w << 6;

  floatx4 acc[4][4];
#pragma unroll
  for (int i = 0; i < 4; i++)
#pragma unroll
    for (int jj = 0; jj < 4; jj++)
#pragma unroll
      for (int r = 0; r < 4; r++) acc[i][jj][r] = 0.0f;

  for (int kt = 0; kt < 32; kt++) {
    const int k0 = kt << 5;
    __syncthreads();
#pragma unroll
    for (int p = 0; p < 2; p++) {
      int slot = p * 256 + w64 + lane;
      int row = slot >> 2;
      int kc = (slot & 3) ^ (row & 3);
      load_lds16(&A[(size_t)(m0 + row) * D_MODEL + k0 + (kc << 3)],
                 &As[(size_t)(p * 256 + w64) << 3]);
      load_lds16(&Wcat[(size_t)(n0g + row) * D_MODEL + k0 + (kc << 3)],
                 &Bs[(size_t)(p * 256 + w64) << 3]);
    }
    __syncthreads();

    bf16x8 af[4], bfv[4];
#pragma unroll
    for (int mi = 0; mi < 4; mi++) {
      int m = wy + mi * 16 + l15;
      af[mi] = *(const bf16x8*)&As[m * 32 + ((quad ^ (m & 3)) << 3)];
    }
#pragma unroll
    for (int ni = 0; ni < 4; ni++) {
      int n = wx + ni * 16 + l15;
      bfv[ni] = *(const bf16x8*)&Bs[n * 32 + ((quad ^ (n & 3)) << 3)];
    }
#pragma unroll
    for (int mi = 0; mi < 4; mi++)
#pragma unroll
      for (int ni = 0; ni < 4; ni++)
        acc[mi][ni] = __builtin_amdgcn_mfma_f32_16x16x32_bf16(
            af[mi], bfv[ni], acc[mi][ni], 0, 0, 0);
  }

  const float* bias = z == 0 ? bq : (z == 1 ? bk : bv);
  bf16_t* outp      = z == 0 ? qo : (z == 1 ? ko : vo);
  const float scl   = (z == 0) ? QSCALE : 1.0f;
#pragma unroll
  for (int mi = 0; mi < 4; mi++) {
#pragma unroll
    for (int ni = 0; ni < 4; ni++) {
      const int nn = (n0g + wx + ni * 16 + l15) & (D_MODEL - 1);
      const float bvv = bias[nn];
      const int h = nn >> 6, d = nn & 63;
#pragma unroll
      for (int r = 0; r < 4; r++) {
        const int m = m0 + wy + mi * 16 + quad * 4 + r;
        const int b = m >> 11, srow = m & (S_LEN - 1);
        float v = (acc[mi][ni][r] + bvv) * scl;
        if (z < 2) {
          outp[((((size_t)(b * NHEAD + h) << 11) + srow) << 6) + d] = (bf16_t)v;
        } else {
          outp[((((size_t)(b * NHEAD + h) << 6) + d) << 11) + srow] = (bf16_t)v;
        }
      }
    }
  }
}

// ---------------------------------------------------------------------------
// LEGACY QKV (round-0 verified) — fallback when ws_size is too small.
// ---------------------------------------------------------------------------
__global__ __launch_bounds__(256, 3)
void qkv_legacy_kernel(const float* __restrict__ Qi, const float* __restrict__ Ki,
                       const float* __restrict__ Vi, const bf16_t* __restrict__ Wcat,
                       const float* __restrict__ bq, const float* __restrict__ bk,
                       const float* __restrict__ bv,
                       bf16_t* __restrict__ qo, bf16_t* __restrict__ ko,
                       bf16_t* __restrict__ vo)
{
  __shared__ float  Asf[128 * 32];
  __shared__ bf16_t Bs[128 * 32];

  const int L = blockIdx.x + 24 * blockIdx.y;
  const int j = (L >> 3) & 7;
  const int s = ((L >> 6) << 3) | (L & 7);
  const int z = s >> 6;
  const int n0g = (((z << 3) | j)) << 7;
  const int m0 = (s & 63) << 7;

  const float* A = z == 0 ? Qi : (z == 1 ? Ki : Vi);

  const int tid = threadIdx.x;
  const int lane = tid & 63;
  const int w = tid >> 6;
  const int l15 = lane & 15;
  const int quad = lane >> 4;
  const int wy = (w >> 1) << 6;
  const int wx = (w & 1) << 6;
  const int w64 = w << 6;

  floatx4 acc[4][4];
#pragma unroll
  for (int i = 0; i < 4; i++)
#pragma unroll
    for (int jj = 0; jj < 4; jj++)
#pragma unroll
      for (int r = 0; r < 4; r++) acc[i][jj][r] = 0.0f;

  for (int kt = 0; kt < 32; kt++) {
    const int k0 = kt << 5;
    __syncthreads();
#pragma unroll
    for (int p = 0; p < 2; p++) {
      int slot = p * 256 + w64 + lane;
      int row = slot >> 2;
      int kc = (slot & 3) ^ (row & 3);
      load_lds16(&Wcat[(size_t)(n0g + row) * D_MODEL + k0 + (kc << 3)],
                 &Bs[(size_t)(p * 256 + w64) << 3]);
    }
#pragma unroll
    for (int p = 0; p < 4; p++) {
      int sbase = (w << 8) + (p << 6);
      int slot = sbase + lane;
      int row = slot >> 3;
      int ca = (slot & 7) ^ (row & 7);
      load_lds16(&A[(size_t)(m0 + row) * D_MODEL + k0 + (ca << 2)],
                 &Asf[(size_t)sbase << 2]);
    }
    __syncthreads();

    bf16x8 af[4], bfv[4];
#pragma unroll
    for (int mi = 0; mi < 4; mi++) {
      const int m = wy + mi * 16 + l15;
      const int e = m & 7;
      floatx4 f0 = *(const floatx4*)&Asf[(m << 5) + ((((quad << 1))     ^ e) << 2)];
      floatx4 f1 = *(const floatx4*)&Asf[(m << 5) + ((((quad << 1) | 1) ^ e) << 2)];
      bf16x8 o;
      o[0] = (bf16_t)f0[0]; o[1] = (bf16_t)f0[1];
      o[2] = (bf16_t)f0[2]; o[3] = (bf16_t)f0[3];
      o[4] = (bf16_t)f1[0]; o[5] = (bf16_t)f1[1];
      o[6] = (bf16_t)f1[2]; o[7] = (bf16_t)f1[3];
      af[mi] = o;
    }
#pragma unroll
    for (int ni = 0; ni < 4; ni++) {
      int n = wx + ni * 16 + l15;
      bfv[ni] = *(const bf16x8*)&Bs[n * 32 + ((quad ^ (n & 3)) << 3)];
    }
#pragma unroll
    for (int mi = 0; mi < 4; mi++)
#pragma unroll
      for (int ni = 0; ni < 4; ni++)
        acc[mi][ni] = __builtin_amdgcn_mfma_f32_16x16x32_bf16(
            af[mi], bfv[ni], acc[mi][ni], 0, 0, 0);
  }

  const float* bias = z == 0 ? bq : (z == 1 ? bk : bv);
  bf16_t* outp      = z == 0 ? qo : (z == 1 ? ko : vo);
  const float scl   = (z == 0) ? QSCALE : 1.0f;
#pragma unroll
  for (int mi = 0; mi < 4; mi++) {
#pragma unroll
    for (int ni = 0; ni < 4; ni++) {
      const int nn = (n0g + wx + ni * 16 + l15) & (D_MODEL - 1);
      const float bvv = bias[nn];
      const int h = nn >> 6, d = nn & 63;
#pragma unroll
      for (int r = 0; r < 4; r++) {
        const int m = m0 + wy + mi * 16 + quad * 4 + r;
        const int b = m >> 11, srow = m & (S_LEN - 1);
        float v = (acc[mi][ni][r] + bvv) * scl;
        if (z < 2) {
          outp[((((size_t)(b * NHEAD + h) << 11) + srow) << 6) + d] = (bf16_t)v;
        } else {
          outp[((((size_t)(b * NHEAD + h) << 6) + d) << 11) + srow] = (bf16_t)v;
        }
      }
    }
  }
}

// ---------------------------------------------------------------------------
// Output GEMM: out = obuf(bf16) @ Wo + bo, fp32 out. Dual global_load_lds.
// Round-9: __launch_bounds__(256, 4) — more co-resident blocks to cover the
// serial-loop staging latency (grid 512 = 2 rounds at 4/CU headroom).
// ---------------------------------------------------------------------------
__global__ __launch_bounds__(256, 4)
void out_gemm_kernel(const bf16_t* __restrict__ A, const bf16_t* __restrict__ Wt,
                     const float* __restrict__ bias, float* __restrict__ out)
{
  __shared__ bf16_t As[128 * 32];
  __shared__ bf16_t Bs[128 * 32];
  const int L = blockIdx.x + 8 * blockIdx.y;      // 0..511
  const int n0 = (((L >> 3) & 7)) << 7;
  const int m0 = ((((L >> 6) << 3) | (L & 7))) << 7;
  const int tid = threadIdx.x;
  const int lane = tid & 63;
  const int w = tid >> 6;
  const int l15 = lane & 15;
  const int quad = lane >> 4;
  const int wy = (w >> 1) << 6;
  const int wx = (w & 1) << 6;
  const int w64 = w << 6;

  floatx4 acc[4][4];
#pragma unroll
  for (int i = 0; i < 4; i++)
#pragma unroll
    for (int jj = 0; jj < 4; jj++)
#pragma unroll
      for (int r = 0; r < 4; r++) acc[i][jj][r] = 0.0f;

  for (int kt = 0; kt < 32; kt++) {
    const int k0 = kt << 5;
    __syncthreads();
#pragma unroll
    for (int p = 0; p < 2; p++) {
      int slot = p * 256 + w64 + lane;
      int row = slot >> 2;
      int kc = (slot & 3) ^ (row & 3);
      load_lds16(&A[(size_t)(m0 + row) * D_MODEL + k0 + (kc << 3)],
                 &As[(size_t)(p * 256 + w64) << 3]);
      load_lds16(&Wt[(size_t)(n0 + row) * D_MODEL + k0 + (kc << 3)],
                 &Bs[(size_t)(p * 256 + w64) << 3]);
    }
    __syncthreads();

    bf16x8 af[4], bfv[4];
#pragma unroll
    for (int mi = 0; mi < 4; mi++) {
      int m = wy + mi * 16 + l15;
      af[mi] = *(const bf16x8*)&As[m * 32 + ((quad ^ (m & 3)) << 3)];
    }
#pragma unroll
    for (int ni = 0; ni < 4; ni++) {
      int n = wx + ni * 16 + l15;
      bfv[ni] = *(const bf16x8*)&Bs[n * 32 + ((quad ^ (n & 3)) << 3)];
    }
#pragma unroll
    for (int mi = 0; mi < 4; mi++)
#pragma unroll
      for (int ni = 0; ni < 4; ni++)
        acc[mi][ni] = __builtin_amdgcn_mfma_f32_16x16x32_bf16(
            af[mi], bfv[ni], acc[mi][ni], 0, 0, 0);
  }

#pragma unroll
  for (int mi = 0; mi < 4; mi++) {
#pragma unroll
    for (int ni = 0; ni < 4; ni++) {
      const int nbase = n0 + wx + ni * 16 + l15;
      const float bv = bias[nbase];
#pragma unroll
      for (int r = 0; r < 4; r++) {
        const int m = m0 + wy + mi * 16 + quad * 4 + r;
        out[((size_t)m << 10) + nbase] = acc[mi][ni][r] + bv;
      }
    }
  }
}

// ---------------------------------------------------------------------------
// Causal flash attention, S^T formulation, BALANCED pairing.
// XCD-clustering remap + setprio + defer-max (round-4/8 verified).
// Round-9: V-fragment ds_reads (bvv) HOISTED above the QK^T MFMA — they
// depend only on cV (stable for the whole body), so their LDS latency now
// hides under the entire softmax instead of sitting on the PV critical path.
// ---------------------------------------------------------------------------
__global__ __launch_bounds__(256, 4)
void attn_kernel(const bf16_t* __restrict__ qp, const bf16_t* __restrict__ kp,
                 const bf16_t* __restrict__ vtp, bf16_t* __restrict__ ob)
{
  __shared__ bf16_t Kt0[64 * 64];
  __shared__ bf16_t Kt1[64 * 64];
  __shared__ bf16_t Vt0[64 * 64];
  __shared__ bf16_t Vt1[64 * 64];

  const int lin = blockIdx.x + (blockIdx.y << 4);   // 0..1023
  const int pair = (lin >> 3) & 15;                 // 0..15
  const int bh = (lin & 7) | ((lin >> 7) << 3);     // 0..63
  const int tid = threadIdx.x;
  const int w = tid >> 6;
  const int lane = tid & 63;
  const int l15 = lane & 15;
  const int quad = lane >> 4;

  const bf16_t* Qh = qp + ((size_t)bh << 17);
  const bf16_t* Kh = kp + ((size_t)bh << 17);
  const bf16_t* Vh = vtp + ((size_t)bh << 17);   // [64][2048]
  const int b = bh >> 4, h = bh & 15;

  auto stage = [&](int k0s, bf16_t* dK, bf16_t* dV) {
#pragma unroll
    for (int p = 0; p < 2; p++) {
      const int sbase = (w << 7) + (p << 6);
      const int slot = sbase + lane;
      const int row = slot >> 3;
      const int c = (slot & 7) ^ (row & 7);
      load_lds16(&Kh[((size_t)(k0s + row) << 6) + (c << 3)], &dK[sbase << 3]);
      load_lds16(&Vh[((size_t)row << 11) + k0s + (c << 3)], &dV[sbase << 3]);
    }
  };

  int par = 0;   // global tile-counter parity: current buffer index

  auto phase = [&](int qt, bool prefetch_next_phase) {
    const int q0 = qt << 6;
    const int qbase = q0 + (w << 4);       // wave's 16 q-rows
    const int nkb = qt + 1;

    bf16x8 qf[2];
#pragma unroll
    for (int ks = 0; ks < 2; ks++)
      qf[ks] = *(const bf16x8*)&Qh[(size_t)(qbase + l15) * DK +
                                   ks * 32 + (quad << 3)];

    floatx4 acc_o[4];
    float m_i = -1e30f, l_i = 0.0f;
#pragma unroll
    for (int nd = 0; nd < 4; nd++)
#pragma unroll
      for (int r = 0; r < 4; r++) acc_o[nd][r] = 0.0f;

    for (int kb = 0; kb < nkb; kb++) {
      const int k0 = kb << 6;
      __syncthreads();   // drains this tile's gll (issued one body ago)

      const bf16_t* cK = par ? Kt1 : Kt0;
      const bf16_t* cV = par ? Vt1 : Vt0;
      bf16_t* nK = par ? Kt0 : Kt1;
      bf16_t* nV = par ? Vt0 : Vt1;

      if (kb + 1 < nkb)             stage((kb + 1) << 6, nK, nV);
      else if (prefetch_next_phase) stage(0, nK, nV);

      bf16x8 bk[2][4], bvv[2][4];
#pragma unroll
      for (int ks = 0; ks < 2; ks++)
#pragma unroll
        for (int ni = 0; ni < 4; ni++) {
          const int row = ni * 16 + l15;
          const int cp = ((ks << 2) + quad) ^ (row & 7);
          bk[ks][ni] = *(const bf16x8*)&cK[(row << 6) + (cp << 3)];
        }
      // V reads hoisted: latency hides under QK^T + softmax below.
#pragma unroll
      for (int ks = 0; ks < 2; ks++)
#pragma unroll
        for (int nd = 0; nd < 4; nd++) {
          const int row = nd * 16 + l15;
          const int cp = ((ks << 2) + quad) ^ (row & 7);
          bvv[ks][nd] = *(const bf16x8*)&cV[(row << 6) + (cp << 3)];
        }

      floatx4 st[4];
#pragma unroll
      for (int ni = 0; ni < 4; ni++)
#pragma unroll
        for (int r = 0; r < 4; r++) st[ni][r] = 0.0f;
      __builtin_amdgcn_s_setprio(1);
#pragma unroll
      for (int ks = 0; ks < 2; ks++)
#pragma unroll
        for (int ni = 0; ni < 4; ni++)
          st[ni] = __builtin_amdgcn_mfma_f32_16x16x32_bf16(
              bk[ks][ni], qf[ks], st[ni], 0, 0, 0);
      __builtin_amdgcn_s_setprio(0);

      if (k0 + 63 > qbase) {
        const int qrow = qbase + l15;
#pragma unroll
        for (int ni = 0; ni < 4; ni++) {
          const int keyb = k0 + ni * 16 + quad * 4;
#pragma unroll
          for (int r = 0; r < 4; r++)
            if (keyb + r > qrow) st[ni][r] = -1e30f;
        }
      }

      float v = st[0][0];
#pragma unroll
      for (int ni = 0; ni < 4; ni++)
#pragma unroll
        for (int r = 0; r < 4; r++) v = fmaxf(v, st[ni][r]);
      v = fmaxf(v, __shfl_xor(v, 16));
      v = fmaxf(v, __shfl_xor(v, 32));

      // Defer-max (T13): skip rescale when tile max doesn't grow past THR.
      if (!__all(v <= m_i + 5.0f)) {
        const float mn = fmaxf(m_i, v);
        const float alpha = __builtin_amdgcn_exp2f(m_i - mn);
        m_i = mn;
        l_i *= alpha;
#pragma unroll
        for (int r = 0; r < 4; r++) {
          float ab = bperm_f((quad * 4 + r) << 2, alpha);
#pragma unroll
          for (int nd = 0; nd < 4; nd++) acc_o[nd][r] *= ab;
        }
      }

      unsigned pd[4][2];
      float ssum = 0.0f;
#pragma unroll
      for (int c = 0; c < 4; c++)
#pragma unroll
        for (int hh = 0; hh < 2; hh++) {
          float p0 = __builtin_amdgcn_exp2f(st[c][2 * hh]     - m_i);
          float p1 = __builtin_amdgcn_exp2f(st[c][2 * hh + 1] - m_i);
          ssum += p0 + p1;
          pd[c][hh] = pack_bf16(p0, p1);
        }
      ssum += __shfl_xor(ssum, 16);
      ssum += __shfl_xor(ssum, 32);
      l_i += ssum;

      union AV { unsigned u[4]; bf16x8 v; };
      AV av[2];
#pragma unroll
      for (int ks = 0; ks < 2; ks++)
#pragma unroll
        for (int i = 0; i < 4; i++) {
          const int addr = ((((2 * quad + (i >> 1)) & 3) << 4) | l15) << 2;
          int lo = __builtin_amdgcn_ds_bpermute(addr, (int)pd[ks * 2][i & 1]);
          int hi = __builtin_amdgcn_ds_bpermute(addr, (int)pd[ks * 2 + 1][i & 1]);
          av[ks].u[i] = (unsigned)(quad >= 2 ? hi : lo);
        }

#pragma unroll
      for (int ks = 0; ks < 2; ks++) {
        __builtin_amdgcn_s_setprio(1);
#pragma unroll
        for (int nd = 0; nd < 4; nd++)
          acc_o[nd] = __builtin_amdgcn_mfma_f32_16x16x32_bf16(
              av[ks].v, bvv[ks][nd], acc_o[nd], 0, 0, 0);
        __builtin_amdgcn_s_setprio(0);
      }

      par ^= 1;
    }

    const float inv = 1.0f / l_i;
#pragma unroll
    for (int r = 0; r < 4; r++) {
      const float linv = bperm_f((quad * 4 + r) << 2, inv);
      const int sRow = qbase + quad * 4 + r;
#pragma unroll
      for (int nd = 0; nd < 4; nd++) {
        const int d = nd * 16 + l15;
        ob[(((size_t)(b * S_LEN + sRow)) << 10) + h * 64 + d] =
            (bf16_t)(acc_o[nd][r] * linv);
      }
    }
  };

  stage(0, Kt0, Vt0);            // tile 0 of phase A into buffer 0
  phase(31 - pair, true);        // big tile first; prefetch B's tile 0 at seam
  phase(pair, false);            // total bodies = (32-p) + (p+1) = 33, uniform
}

// ---------------------------------------------------------------------------
extern "C" void kernel_launch(void* const* d_in, const int* in_sizes, int n_in,
                              void* d_out, int out_size, void* d_ws, size_t ws_size,
                              hipStream_t stream)
{
  (void)in_sizes; (void)n_in; (void)out_size;
  const float* Q  = (const float*)d_in[0];
  const float* K  = (const float*)d_in[1];
  const float* V  = (const float*)d_in[2];
  const float* Wq = (const float*)d_in[4];
  const float* bq = (const float*)d_in[5];
  const float* Wk = (const float*)d_in[6];
  const float* bk = (const float*)d_in[7];
  const float* Wv = (const float*)d_in[8];
  const float* bv = (const float*)d_in[9];
  const float* Wo = (const float*)d_in[10];
  const float* bo = (const float*)d_in[11];
  float* out = (float*)d_out;

  const size_t NELT = (size_t)MROWS * D_MODEL;        // 8 Mi elements
  const size_t WELT = (size_t)D_MODEL * D_MODEL;      // 1 Mi elements

  // Layout (104 MB): qp|kp|vtp (48MB) | weights (8MB) | abf (48MB).
  // obuf ALIASES abf (abf dead after qkv; obuf born after).
  const size_t need_new = (3 * NELT + 4 * WELT + 3 * NELT) * sizeof(bf16_t);

  bf16_t* qp   = (bf16_t*)d_ws;
  bf16_t* kp   = qp + NELT;
  bf16_t* vtp  = kp + NELT;
  bf16_t* wqt  = vtp + NELT;
  bf16_t* wkt  = wqt + WELT;
  bf16_t* wvt  = wkt + WELT;
  bf16_t* wot  = wvt + WELT;
  bf16_t* abf  = wot + WELT;       // [3][8192][1024] bf16 (new path only)
  bf16_t* obuf = abf;              // alias: lives in abf's first 16MB

  dim3 blk(256);

  if (ws_size >= need_new) {
    prep_kernel<<<dim3(4096, 4), blk, 0, stream>>>(
        Q, K, V, abf, Wq, Wk, Wv, Wo, wqt, wkt, wvt, wot);
    qkv_bf16_kernel<<<dim3(3 * D_MODEL / 128, MROWS / 128), blk, 0, stream>>>(
        abf, wqt, bq, bk, bv, qp, kp, vtp);
  } else {
    // Fallback (72 MB, round-0 verified): obuf sits where abf would start.
    transpose_w_kernel<<<dim3(16, 16, 4), blk, 0, stream>>>(
        Wq, Wk, Wv, Wo, wqt, wkt, wvt, wot);
    qkv_legacy_kernel<<<dim3(3 * D_MODEL / 128, MROWS / 128), blk, 0, stream>>>(
        Q, K, V, wqt, bq, bk, bv, qp, kp, vtp);
  }

  attn_kernel<<<dim3(16, BATCH * NHEAD), blk, 0, stream>>>(qp, kp, vtp, obuf);

  out_gemm_kernel<<<dim3(D_MODEL / 128, MROWS / 128), blk, 0, stream>>>(
      obuf, wot, bo, out);
}

// Round 10
// 353.163 us; speedup vs baseline: 2.0611x; 2.0611x over previous
//
#include <hip/hip_runtime.h>

typedef __bf16 bf16_t;
typedef __bf16 bf16x8 __attribute__((ext_vector_type(8)));
typedef __bf16 bf16x4 __attribute__((ext_vector_type(4)));
typedef float  floatx4 __attribute__((ext_vector_type(4)));

#define D_MODEL 1024
#define S_LEN   2048
#define NHEAD   16
#define DK      64
#define BATCH   4
#define MROWS   (BATCH * S_LEN)   // 8192
// 1/sqrt(64) * log2(e): fold into Q so scores arrive in exp2 domain
#define QSCALE  0.18033688011112042f

__device__ __forceinline__ void load_lds16(const void* gsrc, void* ldst) {
  __builtin_amdgcn_global_load_lds(
      (const __attribute__((address_space(1))) void*)gsrc,
      (__attribute__((address_space(3))) void*)ldst, 16, 0, 0);
}

__device__ __forceinline__ unsigned pack_bf16(float a, float b) {
  union { bf16_t h[2]; unsigned u; } t;
  t.h[0] = (bf16_t)a; t.h[1] = (bf16_t)b;
  return t.u;
}

__device__ __forceinline__ float bperm_f(int addr, float v) {
  union { float f; int i; } in, out;
  in.f = v;
  out.i = __builtin_amdgcn_ds_bpermute(addr, in.i);
  return out.f;
}

// ---------------------------------------------------------------------------
// MERGED prep kernel:
//   planes y=0..2: fp32->bf16 convert of Q/K/V into abf [3][8192][1024]
//   plane  y=3, x<1024: weight transpose+cvt (round-0-verified body).
// ---------------------------------------------------------------------------
__global__ __launch_bounds__(256)
void prep_kernel(const float* __restrict__ Q, const float* __restrict__ K,
                 const float* __restrict__ V, bf16_t* __restrict__ Abf,
                 const float* __restrict__ W0, const float* __restrict__ W1,
                 const float* __restrict__ W2, const float* __restrict__ W3,
                 bf16_t* __restrict__ T0, bf16_t* __restrict__ T1,
                 bf16_t* __restrict__ T2, bf16_t* __restrict__ T3)
{
  const int plane = blockIdx.y;
  const int tid = threadIdx.x;

  if (plane < 3) {
    const float* src = plane == 0 ? Q : (plane == 1 ? K : V);
    bf16_t* dst = Abf + ((size_t)plane << 23);
    const size_t off = ((size_t)blockIdx.x * 256 + tid) * 8;
    floatx4 a = *(const floatx4*)&src[off];
    floatx4 b = *(const floatx4*)&src[off + 4];
    bf16x8 o;
    o[0] = (bf16_t)a[0]; o[1] = (bf16_t)a[1];
    o[2] = (bf16_t)a[2]; o[3] = (bf16_t)a[3];
    o[4] = (bf16_t)b[0]; o[5] = (bf16_t)b[1];
    o[6] = (bf16_t)b[2]; o[7] = (bf16_t)b[3];
    *(bf16x8*)&dst[off] = o;
    return;
  }

  // plane == 3: weight transpose. 1024 active blocks.
  const int bx = blockIdx.x;
  if (bx >= 1024) return;
  const int z = bx >> 8;
  const float* W = z == 0 ? W0 : (z == 1 ? W1 : (z == 2 ? W2 : W3));
  bf16_t* Wt     = z == 0 ? T0 : (z == 1 ? T1 : (z == 2 ? T2 : T3));

  __shared__ float tile[64][65];
  const int x0 = (bx & 15) * 64;          // n
  const int y0 = ((bx >> 4) & 15) * 64;   // k
  const int r = tid >> 4;
  const int c = (tid & 15) << 2;
#pragma unroll
  for (int p = 0; p < 4; p++) {
    floatx4 v = *(const floatx4*)&W[(size_t)(y0 + p * 16 + r) * D_MODEL + x0 + c];
    tile[p * 16 + r][c + 0] = v[0];
    tile[p * 16 + r][c + 1] = v[1];
    tile[p * 16 + r][c + 2] = v[2];
    tile[p * 16 + r][c + 3] = v[3];
  }
  __syncthreads();
#pragma unroll
  for (int p = 0; p < 4; p++) {
    int row = p * 16 + r;
    bf16x4 o;
    o[0] = (bf16_t)tile[c + 0][row];
    o[1] = (bf16_t)tile[c + 1][row];
    o[2] = (bf16_t)tile[c + 2][row];
    o[3] = (bf16_t)tile[c + 3][row];
    *(bf16x4*)&Wt[(size_t)(x0 + row) * D_MODEL + y0 + c] = o;
  }
}

// ---------------------------------------------------------------------------
// Standalone weight transpose (fallback path only).
// ---------------------------------------------------------------------------
__global__ __launch_bounds__(256)
void transpose_w_kernel(const float* __restrict__ W0, const float* __restrict__ W1,
                        const float* __restrict__ W2, const float* __restrict__ W3,
                        bf16_t* __restrict__ T0, bf16_t* __restrict__ T1,
                        bf16_t* __restrict__ T2, bf16_t* __restrict__ T3)
{
  const int z = blockIdx.z;
  const float* W = z == 0 ? W0 : (z == 1 ? W1 : (z == 2 ? W2 : W3));
  bf16_t* Wt     = z == 0 ? T0 : (z == 1 ? T1 : (z == 2 ? T2 : T3));

  __shared__ float tile[64][65];
  const int x0 = blockIdx.x * 64;         // n
  const int y0 = blockIdx.y * 64;         // k
  const int tid = threadIdx.x;
  const int r = tid >> 4;
  const int c = (tid & 15) << 2;
#pragma unroll
  for (int p = 0; p < 4; p++) {
    floatx4 v = *(const floatx4*)&W[(size_t)(y0 + p * 16 + r) * D_MODEL + x0 + c];
    tile[p * 16 + r][c + 0] = v[0];
    tile[p * 16 + r][c + 1] = v[1];
    tile[p * 16 + r][c + 2] = v[2];
    tile[p * 16 + r][c + 3] = v[3];
  }
  __syncthreads();
#pragma unroll
  for (int p = 0; p < 4; p++) {
    int row = p * 16 + r;
    bf16x4 o;
    o[0] = (bf16_t)tile[c + 0][row];
    o[1] = (bf16_t)tile[c + 1][row];
    o[2] = (bf16_t)tile[c + 2][row];
    o[3] = (bf16_t)tile[c + 3][row];
    *(bf16x4*)&Wt[(size_t)(x0 + row) * D_MODEL + y0 + c] = o;
  }
}

// ---------------------------------------------------------------------------
// QKV projection, m97-structure, ALL-bf16. Round-10:
//   * NO min-waves bound (round-9's (256,6) capped VGPR at 40 -> acc spilled,
//     1.3 GB scratch traffic, 5x slowdown. 84-116 VGPR needs the default cap).
//   * BK=32 -> 64: 32 KB LDS, 16 K-iterations; per barrier-pair now
//     8 gll + 16 ds_read + 32 MFMA (vs 4/8/16) -> the per-iteration barrier
//     drain (m233's ~20% stall) is amortized over 2x the compute.
//   Staging swizzle c=(slot&7)^(row&7) and fragment read
//   ((ks<<2)+quad)^(row&7) are byte-identical to the attn kernel's
//   in-harness-verified K-tile pattern ([128] rows here vs [64] there).
// ---------------------------------------------------------------------------
__global__ __launch_bounds__(256)
void qkv_bf16_kernel(const bf16_t* __restrict__ Abf, const bf16_t* __restrict__ Wcat,
                     const float* __restrict__ bq, const float* __restrict__ bk,
                     const float* __restrict__ bv,
                     bf16_t* __restrict__ qo, bf16_t* __restrict__ ko,
                     bf16_t* __restrict__ vo)
{
  __shared__ bf16_t As[128 * 64];
  __shared__ bf16_t Bs[128 * 64];

  // XCD-locality decode (legacy-verified): the 8 blocks sharing one (z,y)
  // A-stripe land on one XCD (L % 8 == s % 8).
  const int L = blockIdx.x + 24 * blockIdx.y;     // 0..1535
  const int j = (L >> 3) & 7;
  const int s = ((L >> 6) << 3) | (L & 7);        // stripe 0..191
  const int z = s >> 6;                           // projection
  const int n0g = (((z << 3) | j)) << 7;          // global n over 3072
  const int m0 = (s & 63) << 7;

  const bf16_t* A = Abf + ((size_t)z << 23);

  const int tid = threadIdx.x;
  const int lane = tid & 63;
  const int w = tid >> 6;
  const int l15 = lane & 15;
  const int quad = lane >> 4;
  const int wy = (w >> 1) << 6;
  const int wx = (w & 1) << 6;
  const int w64 = w << 6;

  floatx4 acc[4][4];
#pragma unroll
  for (int i = 0; i < 4; i++)
#pragma unroll
    for (int jj = 0; jj < 4; jj++)
#pragma unroll
      for (int r = 0; r < 4; r++) acc[i][jj][r] = 0.0f;

  for (int kt = 0; kt < 16; kt++) {
    const int k0 = kt << 6;
    __syncthreads();
#pragma unroll
    for (int p = 0; p < 4; p++) {
      int slot = p * 256 + w64 + lane;   // 0..1023
      int row = slot >> 3;               // 0..127
      int c = (slot & 7) ^ (row & 7);
      load_lds16(&A[(size_t)(m0 + row) * D_MODEL + k0 + (c << 3)],
                 &As[(size_t)(p * 256 + w64) << 3]);
      load_lds16(&Wcat[(size_t)(n0g + row) * D_MODEL + k0 + (c << 3)],
                 &Bs[(size_t)(p * 256 + w64) << 3]);
    }
    __syncthreads();

#pragma unroll
    for (int ks = 0; ks < 2; ks++) {
      bf16x8 af[4], bfv[4];
#pragma unroll
      for (int mi = 0; mi < 4; mi++) {
        int m = wy + mi * 16 + l15;
        af[mi] = *(const bf16x8*)&As[(m << 6) + ((((ks << 2) + quad) ^ (m & 7)) << 3)];
      }
#pragma unroll
      for (int ni = 0; ni < 4; ni++) {
        int n = wx + ni * 16 + l15;
        bfv[ni] = *(const bf16x8*)&Bs[(n << 6) + ((((ks << 2) + quad) ^ (n & 7)) << 3)];
      }
#pragma unroll
      for (int mi = 0; mi < 4; mi++)
#pragma unroll
        for (int ni = 0; ni < 4; ni++)
          acc[mi][ni] = __builtin_amdgcn_mfma_f32_16x16x32_bf16(
              af[mi], bfv[ni], acc[mi][ni], 0, 0, 0);
    }
  }

  const float* bias = z == 0 ? bq : (z == 1 ? bk : bv);
  bf16_t* outp      = z == 0 ? qo : (z == 1 ? ko : vo);
  const float scl   = (z == 0) ? QSCALE : 1.0f;
#pragma unroll
  for (int mi = 0; mi < 4; mi++) {
#pragma unroll
    for (int ni = 0; ni < 4; ni++) {
      const int nn = (n0g + wx + ni * 16 + l15) & (D_MODEL - 1);
      const float bvv = bias[nn];
      const int h = nn >> 6, d = nn & 63;
#pragma unroll
      for (int r = 0; r < 4; r++) {
        const int m = m0 + wy + mi * 16 + quad * 4 + r;
        const int b = m >> 11, srow = m & (S_LEN - 1);
        float v = (acc[mi][ni][r] + bvv) * scl;
        if (z < 2) {
          outp[((((size_t)(b * NHEAD + h) << 11) + srow) << 6) + d] = (bf16_t)v;
        } else {
          outp[((((size_t)(b * NHEAD + h) << 6) + d) << 11) + srow] = (bf16_t)v;
        }
      }
    }
  }
}

// ---------------------------------------------------------------------------
// LEGACY QKV (round-0 verified) — fallback when ws_size is too small.
// ---------------------------------------------------------------------------
__global__ __launch_bounds__(256, 3)
void qkv_legacy_kernel(const float* __restrict__ Qi, const float* __restrict__ Ki,
                       const float* __restrict__ Vi, const bf16_t* __restrict__ Wcat,
                       const float* __restrict__ bq, const float* __restrict__ bk,
                       const float* __restrict__ bv,
                       bf16_t* __restrict__ qo, bf16_t* __restrict__ ko,
                       bf16_t* __restrict__ vo)
{
  __shared__ float  Asf[128 * 32];
  __shared__ bf16_t Bs[128 * 32];

  const int L = blockIdx.x + 24 * blockIdx.y;
  const int j = (L >> 3) & 7;
  const int s = ((L >> 6) << 3) | (L & 7);
  const int z = s >> 6;
  const int n0g = (((z << 3) | j)) << 7;
  const int m0 = (s & 63) << 7;

  const float* A = z == 0 ? Qi : (z == 1 ? Ki : Vi);

  const int tid = threadIdx.x;
  const int lane = tid & 63;
  const int w = tid >> 6;
  const int l15 = lane & 15;
  const int quad = lane >> 4;
  const int wy = (w >> 1) << 6;
  const int wx = (w & 1) << 6;
  const int w64 = w << 6;

  floatx4 acc[4][4];
#pragma unroll
  for (int i = 0; i < 4; i++)
#pragma unroll
    for (int jj = 0; jj < 4; jj++)
#pragma unroll
      for (int r = 0; r < 4; r++) acc[i][jj][r] = 0.0f;

  for (int kt = 0; kt < 32; kt++) {
    const int k0 = kt << 5;
    __syncthreads();
#pragma unroll
    for (int p = 0; p < 2; p++) {
      int slot = p * 256 + w64 + lane;
      int row = slot >> 2;
      int kc = (slot & 3) ^ (row & 3);
      load_lds16(&Wcat[(size_t)(n0g + row) * D_MODEL + k0 + (kc << 3)],
                 &Bs[(size_t)(p * 256 + w64) << 3]);
    }
#pragma unroll
    for (int p = 0; p < 4; p++) {
      int sbase = (w << 8) + (p << 6);
      int slot = sbase + lane;
      int row = slot >> 3;
      int ca = (slot & 7) ^ (row & 7);
      load_lds16(&A[(size_t)(m0 + row) * D_MODEL + k0 + (ca << 2)],
                 &Asf[(size_t)sbase << 2]);
    }
    __syncthreads();

    bf16x8 af[4], bfv[4];
#pragma unroll
    for (int mi = 0; mi < 4; mi++) {
      const int m = wy + mi * 16 + l15;
      const int e = m & 7;
      floatx4 f0 = *(const floatx4*)&Asf[(m << 5) + ((((quad << 1))     ^ e) << 2)];
      floatx4 f1 = *(const floatx4*)&Asf[(m << 5) + ((((quad << 1) | 1) ^ e) << 2)];
      bf16x8 o;
      o[0] = (bf16_t)f0[0]; o[1] = (bf16_t)f0[1];
      o[2] = (bf16_t)f0[2]; o[3] = (bf16_t)f0[3];
      o[4] = (bf16_t)f1[0]; o[5] = (bf16_t)f1[1];
      o[6] = (bf16_t)f1[2]; o[7] = (bf16_t)f1[3];
      af[mi] = o;
    }
#pragma unroll
    for (int ni = 0; ni < 4; ni++) {
      int n = wx + ni * 16 + l15;
      bfv[ni] = *(const bf16x8*)&Bs[n * 32 + ((quad ^ (n & 3)) << 3)];
    }
#pragma unroll
    for (int mi = 0; mi < 4; mi++)
#pragma unroll
      for (int ni = 0; ni < 4; ni++)
        acc[mi][ni] = __builtin_amdgcn_mfma_f32_16x16x32_bf16(
            af[mi], bfv[ni], acc[mi][ni], 0, 0, 0);
  }

  const float* bias = z == 0 ? bq : (z == 1 ? bk : bv);
  bf16_t* outp      = z == 0 ? qo : (z == 1 ? ko : vo);
  const float scl   = (z == 0) ? QSCALE : 1.0f;
#pragma unroll
  for (int mi = 0; mi < 4; mi++) {
#pragma unroll
    for (int ni = 0; ni < 4; ni++) {
      const int nn = (n0g + wx + ni * 16 + l15) & (D_MODEL - 1);
      const float bvv = bias[nn];
      const int h = nn >> 6, d = nn & 63;
#pragma unroll
      for (int r = 0; r < 4; r++) {
        const int m = m0 + wy + mi * 16 + quad * 4 + r;
        const int b = m >> 11, srow = m & (S_LEN - 1);
        float v = (acc[mi][ni][r] + bvv) * scl;
        if (z < 2) {
          outp[((((size_t)(b * NHEAD + h) << 11) + srow) << 6) + d] = (bf16_t)v;
        } else {
          outp[((((size_t)(b * NHEAD + h) << 6) + d) << 11) + srow] = (bf16_t)v;
        }
      }
    }
  }
}

// ---------------------------------------------------------------------------
// Output GEMM: out = obuf(bf16) @ Wo + bo, fp32 out. Dual global_load_lds.
// __launch_bounds__(256, 4): budget 128 VGPR >> the ~84 needed, no spill.
// ---------------------------------------------------------------------------
__global__ __launch_bounds__(256, 4)
void out_gemm_kernel(const bf16_t* __restrict__ A, const bf16_t* __restrict__ Wt,
                     const float* __restrict__ bias, float* __restrict__ out)
{
  __shared__ bf16_t As[128 * 32];
  __shared__ bf16_t Bs[128 * 32];
  const int L = blockIdx.x + 8 * blockIdx.y;      // 0..511
  const int n0 = (((L >> 3) & 7)) << 7;
  const int m0 = ((((L >> 6) << 3) | (L & 7))) << 7;
  const int tid = threadIdx.x;
  const int lane = tid & 63;
  const int w = tid >> 6;
  const int l15 = lane & 15;
  const int quad = lane >> 4;
  const int wy = (w >> 1) << 6;
  const int wx = (w & 1) << 6;
  const int w64 = w << 6;

  floatx4 acc[4][4];
#pragma unroll
  for (int i = 0; i < 4; i++)
#pragma unroll
    for (int jj = 0; jj < 4; jj++)
#pragma unroll
      for (int r = 0; r < 4; r++) acc[i][jj][r] = 0.0f;

  for (int kt = 0; kt < 32; kt++) {
    const int k0 = kt << 5;
    __syncthreads();
#pragma unroll
    for (int p = 0; p < 2; p++) {
      int slot = p * 256 + w64 + lane;
      int row = slot >> 2;
      int kc = (slot & 3) ^ (row & 3);
      load_lds16(&A[(size_t)(m0 + row) * D_MODEL + k0 + (kc << 3)],
                 &As[(size_t)(p * 256 + w64) << 3]);
      load_lds16(&Wt[(size_t)(n0 + row) * D_MODEL + k0 + (kc << 3)],
                 &Bs[(size_t)(p * 256 + w64) << 3]);
    }
    __syncthreads();

    bf16x8 af[4], bfv[4];
#pragma unroll
    for (int mi = 0; mi < 4; mi++) {
      int m = wy + mi * 16 + l15;
      af[mi] = *(const bf16x8*)&As[m * 32 + ((quad ^ (m & 3)) << 3)];
    }
#pragma unroll
    for (int ni = 0; ni < 4; ni++) {
      int n = wx + ni * 16 + l15;
      bfv[ni] = *(const bf16x8*)&Bs[n * 32 + ((quad ^ (n & 3)) << 3)];
    }
#pragma unroll
    for (int mi = 0; mi < 4; mi++)
#pragma unroll
      for (int ni = 0; ni < 4; ni++)
        acc[mi][ni] = __builtin_amdgcn_mfma_f32_16x16x32_bf16(
            af[mi], bfv[ni], acc[mi][ni], 0, 0, 0);
  }

#pragma unroll
  for (int mi = 0; mi < 4; mi++) {
#pragma unroll
    for (int ni = 0; ni < 4; ni++) {
      const int nbase = n0 + wx + ni * 16 + l15;
      const float bv = bias[nbase];
#pragma unroll
      for (int r = 0; r < 4; r++) {
        const int m = m0 + wy + mi * 16 + quad * 4 + r;
        out[((size_t)m << 10) + nbase] = acc[mi][ni][r] + bv;
      }
    }
  }
}

// ---------------------------------------------------------------------------
// Causal flash attention, S^T formulation, BALANCED pairing.
// XCD-clustering remap + setprio + defer-max + hoisted V-reads.
// ---------------------------------------------------------------------------
__global__ __launch_bounds__(256, 4)
void attn_kernel(const bf16_t* __restrict__ qp, const bf16_t* __restrict__ kp,
                 const bf16_t* __restrict__ vtp, bf16_t* __restrict__ ob)
{
  __shared__ bf16_t Kt0[64 * 64];
  __shared__ bf16_t Kt1[64 * 64];
  __shared__ bf16_t Vt0[64 * 64];
  __shared__ bf16_t Vt1[64 * 64];

  const int lin = blockIdx.x + (blockIdx.y << 4);   // 0..1023
  const int pair = (lin >> 3) & 15;                 // 0..15
  const int bh = (lin & 7) | ((lin >> 7) << 3);     // 0..63
  const int tid = threadIdx.x;
  const int w = tid >> 6;
  const int lane = tid & 63;
  const int l15 = lane & 15;
  const int quad = lane >> 4;

  const bf16_t* Qh = qp + ((size_t)bh << 17);
  const bf16_t* Kh = kp + ((size_t)bh << 17);
  const bf16_t* Vh = vtp + ((size_t)bh << 17);   // [64][2048]
  const int b = bh >> 4, h = bh & 15;

  auto stage = [&](int k0s, bf16_t* dK, bf16_t* dV) {
#pragma unroll
    for (int p = 0; p < 2; p++) {
      const int sbase = (w << 7) + (p << 6);
      const int slot = sbase + lane;
      const int row = slot >> 3;
      const int c = (slot & 7) ^ (row & 7);
      load_lds16(&Kh[((size_t)(k0s + row) << 6) + (c << 3)], &dK[sbase << 3]);
      load_lds16(&Vh[((size_t)row << 11) + k0s + (c << 3)], &dV[sbase << 3]);
    }
  };

  int par = 0;   // global tile-counter parity: current buffer index

  auto phase = [&](int qt, bool prefetch_next_phase) {
    const int q0 = qt << 6;
    const int qbase = q0 + (w << 4);       // wave's 16 q-rows
    const int nkb = qt + 1;

    bf16x8 qf[2];
#pragma unroll
    for (int ks = 0; ks < 2; ks++)
      qf[ks] = *(const bf16x8*)&Qh[(size_t)(qbase + l15) * DK +
                                   ks * 32 + (quad << 3)];

    floatx4 acc_o[4];
    float m_i = -1e30f, l_i = 0.0f;
#pragma unroll
    for (int nd = 0; nd < 4; nd++)
#pragma unroll
      for (int r = 0; r < 4; r++) acc_o[nd][r] = 0.0f;

    for (int kb = 0; kb < nkb; kb++) {
      const int k0 = kb << 6;
      __syncthreads();   // drains this tile's gll (issued one body ago)

      const bf16_t* cK = par ? Kt1 : Kt0;
      const bf16_t* cV = par ? Vt1 : Vt0;
      bf16_t* nK = par ? Kt0 : Kt1;
      bf16_t* nV = par ? Vt0 : Vt1;

      if (kb + 1 < nkb)             stage((kb + 1) << 6, nK, nV);
      else if (prefetch_next_phase) stage(0, nK, nV);

      bf16x8 bk[2][4], bvv[2][4];
#pragma unroll
      for (int ks = 0; ks < 2; ks++)
#pragma unroll
        for (int ni = 0; ni < 4; ni++) {
          const int row = ni * 16 + l15;
          const int cp = ((ks << 2) + quad) ^ (row & 7);
          bk[ks][ni] = *(const bf16x8*)&cK[(row << 6) + (cp << 3)];
        }
      // V reads hoisted: latency hides under QK^T + softmax below.
#pragma unroll
      for (int ks = 0; ks < 2; ks++)
#pragma unroll
        for (int nd = 0; nd < 4; nd++) {
          const int row = nd * 16 + l15;
          const int cp = ((ks << 2) + quad) ^ (row & 7);
          bvv[ks][nd] = *(const bf16x8*)&cV[(row << 6) + (cp << 3)];
        }

      floatx4 st[4];
#pragma unroll
      for (int ni = 0; ni < 4; ni++)
#pragma unroll
        for (int r = 0; r < 4; r++) st[ni][r] = 0.0f;
      __builtin_amdgcn_s_setprio(1);
#pragma unroll
      for (int ks = 0; ks < 2; ks++)
#pragma unroll
        for (int ni = 0; ni < 4; ni++)
          st[ni] = __builtin_amdgcn_mfma_f32_16x16x32_bf16(
              bk[ks][ni], qf[ks], st[ni], 0, 0, 0);
      __builtin_amdgcn_s_setprio(0);

      if (k0 + 63 > qbase) {
        const int qrow = qbase + l15;
#pragma unroll
        for (int ni = 0; ni < 4; ni++) {
          const int keyb = k0 + ni * 16 + quad * 4;
#pragma unroll
          for (int r = 0; r < 4; r++)
            if (keyb + r > qrow) st[ni][r] = -1e30f;
        }
      }

      float v = st[0][0];
#pragma unroll
      for (int ni = 0; ni < 4; ni++)
#pragma unroll
        for (int r = 0; r < 4; r++) v = fmaxf(v, st[ni][r]);
      v = fmaxf(v, __shfl_xor(v, 16));
      v = fmaxf(v, __shfl_xor(v, 32));

      // Defer-max (T13): skip rescale when tile max doesn't grow past THR.
      if (!__all(v <= m_i + 5.0f)) {
        const float mn = fmaxf(m_i, v);
        const float alpha = __builtin_amdgcn_exp2f(m_i - mn);
        m_i = mn;
        l_i *= alpha;
#pragma unroll
        for (int r = 0; r < 4; r++) {
          float ab = bperm_f((quad * 4 + r) << 2, alpha);
#pragma unroll
          for (int nd = 0; nd < 4; nd++) acc_o[nd][r] *= ab;
        }
      }

      unsigned pd[4][2];
      float ssum = 0.0f;
#pragma unroll
      for (int c = 0; c < 4; c++)
#pragma unroll
        for (int hh = 0; hh < 2; hh++) {
          float p0 = __builtin_amdgcn_exp2f(st[c][2 * hh]     - m_i);
          float p1 = __builtin_amdgcn_exp2f(st[c][2 * hh + 1] - m_i);
          ssum += p0 + p1;
          pd[c][hh] = pack_bf16(p0, p1);
        }
      ssum += __shfl_xor(ssum, 16);
      ssum += __shfl_xor(ssum, 32);
      l_i += ssum;

      union AV { unsigned u[4]; bf16x8 v; };
      AV av[2];
#pragma unroll
      for (int ks = 0; ks < 2; ks++)
#pragma unroll
        for (int i = 0; i < 4; i++) {
          const int addr = ((((2 * quad + (i >> 1)) & 3) << 4) | l15) << 2;
          int lo = __builtin_amdgcn_ds_bpermute(addr, (int)pd[ks * 2][i & 1]);
          int hi = __builtin_amdgcn_ds_bpermute(addr, (int)pd[ks * 2 + 1][i & 1]);
          av[ks].u[i] = (unsigned)(quad >= 2 ? hi : lo);
        }

#pragma unroll
      for (int ks = 0; ks < 2; ks++) {
        __builtin_amdgcn_s_setprio(1);
#pragma unroll
        for (int nd = 0; nd < 4; nd++)
          acc_o[nd] = __builtin_amdgcn_mfma_f32_16x16x32_bf16(
              av[ks].v, bvv[ks][nd], acc_o[nd], 0, 0, 0);
        __builtin_amdgcn_s_setprio(0);
      }

      par ^= 1;
    }

    const float inv = 1.0f / l_i;
#pragma unroll
    for (int r = 0; r < 4; r++) {
      const float linv = bperm_f((quad * 4 + r) << 2, inv);
      const int sRow = qbase + quad * 4 + r;
#pragma unroll
      for (int nd = 0; nd < 4; nd++) {
        const int d = nd * 16 + l15;
        ob[(((size_t)(b * S_LEN + sRow)) << 10) + h * 64 + d] =
            (bf16_t)(acc_o[nd][r] * linv);
      }
    }
  };

  stage(0, Kt0, Vt0);            // tile 0 of phase A into buffer 0
  phase(31 - pair, true);        // big tile first; prefetch B's tile 0 at seam
  phase(pair, false);            // total bodies = (32-p) + (p+1) = 33, uniform
}

// ---------------------------------------------------------------------------
extern "C" void kernel_launch(void* const* d_in, const int* in_sizes, int n_in,
                              void* d_out, int out_size, void* d_ws, size_t ws_size,
                              hipStream_t stream)
{
  (void)in_sizes; (void)n_in; (void)out_size;
  const float* Q  = (const float*)d_in[0];
  const float* K  = (const float*)d_in[1];
  const float* V  = (const float*)d_in[2];
  const float* Wq = (const float*)d_in[4];
  const float* bq = (const float*)d_in[5];
  const float* Wk = (const float*)d_in[6];
  const float* bk = (const float*)d_in[7];
  const float* Wv = (const float*)d_in[8];
  const float* bv = (const float*)d_in[9];
  const float* Wo = (const float*)d_in[10];
  const float* bo = (const float*)d_in[11];
  float* out = (float*)d_out;

  const size_t NELT = (size_t)MROWS * D_MODEL;        // 8 Mi elements
  const size_t WELT = (size_t)D_MODEL * D_MODEL;      // 1 Mi elements

  // Layout (104 MB): qp|kp|vtp (48MB) | weights (8MB) | abf (48MB).
  // obuf ALIASES abf (abf dead after qkv; obuf born after).
  const size_t need_new = (3 * NELT + 4 * WELT + 3 * NELT) * sizeof(bf16_t);

  bf16_t* qp   = (bf16_t*)d_ws;
  bf16_t* kp   = qp + NELT;
  bf16_t* vtp  = kp + NELT;
  bf16_t* wqt  = vtp + NELT;
  bf16_t* wkt  = wqt + WELT;
  bf16_t* wvt  = wkt + WELT;
  bf16_t* wot  = wvt + WELT;
  bf16_t* abf  = wot + WELT;       // [3][8192][1024] bf16 (new path only)
  bf16_t* obuf = abf;              // alias: lives in abf's first 16MB

  dim3 blk(256);

  if (ws_size >= need_new) {
    prep_kernel<<<dim3(4096, 4), blk, 0, stream>>>(
        Q, K, V, abf, Wq, Wk, Wv, Wo, wqt, wkt, wvt, wot);
    qkv_bf16_kernel<<<dim3(3 * D_MODEL / 128, MROWS / 128), blk, 0, stream>>>(
        abf, wqt, bq, bk, bv, qp, kp, vtp);
  } else {
    // Fallback (72 MB, round-0 verified): obuf sits where abf would start.
    transpose_w_kernel<<<dim3(16, 16, 4), blk, 0, stream>>>(
        Wq, Wk, Wv, Wo, wqt, wkt, wvt, wot);
    qkv_legacy_kernel<<<dim3(3 * D_MODEL / 128, MROWS / 128), blk, 0, stream>>>(
        Q, K, V, wqt, bq, bk, bv, qp, kp, vtp);
  }

  attn_kernel<<<dim3(16, BATCH * NHEAD), blk, 0, stream>>>(qp, kp, vtp, obuf);

  out_gemm_kernel<<<dim3(D_MODEL / 128, MROWS / 128), blk, 0, stream>>>(
      obuf, wot, bo, out);
}